// Round 7
// baseline (60.750 us; speedup 1.0000x reference)
//
#include <hip/hip_runtime.h>
#include <stdint.h>

#define SCAN_BS 256
#define MOT_BS  256

// ---------------- fused scan + cav-index scatter (ONE kernel, 1 barrier) ----------------
// 243 blocks of 256. Each block redundantly computes its carry = sum(counts[0..chunkStart))
// via strided coalesced loads (L2-resident; total redundancy ~30 MB = free), wave-shuffle
// scans its own chunk, then scatter-writes cavIdx[start..end) = cav.

__global__ __launch_bounds__(SCAN_BS) void scan_scatter_kernel(
    const int* __restrict__ counts, int C, int* __restrict__ cavIdx) {

    __shared__ int cw[SCAN_BS / 64];   // per-wave carry partials
    __shared__ int wv[SCAN_BS / 64];   // per-wave chunk totals

    const int tid  = threadIdx.x;
    const int lane = tid & 63;
    const int wid  = tid >> 6;
    const int gid  = blockIdx.x * SCAN_BS + tid;
    const int chunkStart = blockIdx.x * SCAN_BS;

    const int v = (gid < C) ? counts[gid] : 0;

    // redundant carry over all preceding chunks (coalesced, L2-hit)
    int csum = 0;
    for (int idx = tid; idx < chunkStart; idx += SCAN_BS) csum += counts[idx];
    #pragma unroll
    for (int o = 32; o > 0; o >>= 1) csum += __shfl_down(csum, o, 64);

    // wave-level inclusive scan of v
    int inc = v;
    #pragma unroll
    for (int o = 1; o < 64; o <<= 1) {
        int t = __shfl_up(inc, o, 64);
        if (lane >= o) inc += t;
    }

    if (lane == 0)  cw[wid] = csum;
    if (lane == 63) wv[wid] = inc;
    __syncthreads();

    int base = 0;
    #pragma unroll
    for (int w = 0; w < SCAN_BS / 64; ++w) {
        base += cw[w];
        if (w < wid) base += wv[w];
    }

    if (gid < C) {
        const int end   = base + inc;   // inclusive cumsum
        const int start = end - v;
        for (int s = start; s < end; ++s) cavIdx[s] = gid;
    }
}

// ---------------- main per-object kernel: pure streaming, no LDS, no barrier ----------------
//
// out layout (floats):
//   [0,       8N)  obj_input  [1,N,2,4]
//   [8N,     10N)  query      [1,N,1,2]
//   [10N,    12N)  time_encode[N,2]
//   [12N,    13N)  target_time_diff [N]

__global__ __launch_bounds__(MOT_BS) void motion_kernel(
    const float* __restrict__ bbx, const float* __restrict__ tint,
    const int* __restrict__ cavIdx, int N, float* __restrict__ out) {

    const int stride = gridDim.x * MOT_BS;
    const size_t Ns = (size_t)N;

    for (int i = blockIdx.x * MOT_BS + threadIdx.x; i < N; i += stride) {
        // coalesced cav id; dependent tint gather (wave spans ~4 cavs -> L1 broadcast)
        const int cav = cavIdx[i];
        const float t0 = tint[3 * cav + 0];
        const float t1 = tint[3 * cav + 1];
        const float t2 = tint[3 * cav + 2];

        // direct strided reads: 6 dwords out of each 84 B object window.
        // Every 64B line holds needed bytes -> HBM traffic identical to staged
        // variant; L1 catches the multi-visit per line. Independent of cav chain.
        const float* bp = bbx + (size_t)i * 21;
        const float x0 = bp[0],  y0 = bp[1];
        const float x1 = bp[7],  y1 = bp[8];
        const float x2 = bp[14], y2 = bp[15];

        // td_rep = [t2, t1, t0];  dt = time_encode
        const float dt0 = t1 - t2;
        const float dt1 = t0 - t1;

        // coords (flipped, normalized to last): c0v = f2-f0, c1v = f1-f0, c2v = 0
        const float c0x = x2 - x0, c0y = y2 - y0;
        const float c1x = x1 - x0, c1y = y1 - y0;

        const float d0x = c1x - c0x, d0y = c1y - c0y;
        const float d1x = 0.0f - c1x, d1y = 0.0f - c1y;

        const float s0x = d0x / dt0, s0y = d0y / dt0;
        const float s1x = d1x / dt1, s1y = d1y / dt1;

        const float last_len = 0.0f - (t1 - t0);
        const float safe_len = (last_len == 0.0f) ? 1.0f : last_len;
        const float exx = ((0.0f - c1x) * (0.0f - t0)) / safe_len;
        const float exy = ((0.0f - c1y) * (0.0f - t0)) / safe_len;
        const float qx = (last_len == 0.0f) ? 0.0f : exx;
        const float qy = (last_len == 0.0f) ? 0.0f : exy;

        // ---- coalesced writes ----
        float4* oi = (float4*)out;
        oi[(size_t)i * 2 + 0] = make_float4(d0x, d0y, s0x, s0y);
        oi[(size_t)i * 2 + 1] = make_float4(d1x, d1y, s1x, s1y);

        float2* q  = (float2*)(out + 8 * Ns);
        q[i] = make_float2(qx, qy);

        float2* te = (float2*)(out + 10 * Ns);
        te[i] = make_float2(dt0, dt1);

        out[12 * Ns + (size_t)i] = 0.0f - t0;
    }
}

// ---------------- launch ----------------

extern "C" void kernel_launch(void* const* d_in, const int* in_sizes, int n_in,
                              void* d_out, int out_size, void* d_ws, size_t ws_size,
                              hipStream_t stream) {
    const float* bbx  = (const float*)d_in[0];   // [N,3,7]
    const float* tint = (const float*)d_in[1];   // [C*3]
    const int*   cnt  = (const int*)d_in[2];     // [C]
    float* out = (float*)d_out;

    const int N = in_sizes[0] / 21;
    const int C = in_sizes[2];

    const int nb = (C + SCAN_BS - 1) / SCAN_BS;
    int nob = (N + MOT_BS - 1) / MOT_BS;
    if (nob > 2048) nob = 2048;                  // grid-stride beyond 8 blocks/CU

    int* cavIdx = (int*)d_ws;                    // N ints (~4 MB)

    scan_scatter_kernel<<<nb, SCAN_BS, 0, stream>>>(cnt, C, cavIdx);
    motion_kernel<<<nob, MOT_BS, 0, stream>>>(bbx, tint, cavIdx, N, out);
}

// Round 8
// 59.784 us; speedup vs baseline: 1.0162x; 1.0162x over previous
//
#include <hip/hip_runtime.h>
#include <limits.h>
#include <stdint.h>

#define SCAN_BS 256
#define OBJ_BS  256
#define SLAB_F  (OBJ_BS * 21)     // 5376 floats = 21504 B
#define SLAB_CH (SLAB_F / 256)    // 21 wave-chunks (64 lanes x 16 B)

// ---- global->LDS DMA helper (size must be a literal) ----
__device__ __forceinline__ void gload_lds16(const void* g, void* l) {
    __builtin_amdgcn_global_load_lds(
        (const __attribute__((address_space(1))) uint32_t*)g,
        (__attribute__((address_space(3))) uint32_t*)l, 16, 0, 0);
}

// ---------------- fused scan: ONE kernel, 243 blocks, 1 barrier ----------------
// Redundant cross-chunk carry via coalesced strided sums (counts is L2-resident,
// ~30 MB aggregate redundancy = free); wave-shuffle inclusive scan inside the chunk;
// emits inclusive-cumsum offsets[] and blockCav[] (cav containing each block start).

__global__ __launch_bounds__(SCAN_BS) void scan_fused_kernel(
    const int* __restrict__ counts, int C,
    int* __restrict__ offsets, int* __restrict__ blockCav) {

    __shared__ int cw[SCAN_BS / 64];   // per-wave carry partials
    __shared__ int wv[SCAN_BS / 64];   // per-wave chunk totals

    const int tid  = threadIdx.x;
    const int lane = tid & 63;
    const int wid  = tid >> 6;
    const int gid  = blockIdx.x * SCAN_BS + tid;
    const int chunkStart = blockIdx.x * SCAN_BS;

    const int v = (gid < C) ? counts[gid] : 0;

    // redundant carry over all preceding chunks (coalesced, L2-hit)
    int csum = 0;
    for (int idx = tid; idx < chunkStart; idx += SCAN_BS) csum += counts[idx];
    #pragma unroll
    for (int o = 32; o > 0; o >>= 1) csum += __shfl_down(csum, o, 64);

    // wave-level inclusive scan of v
    int inc = v;
    #pragma unroll
    for (int o = 1; o < 64; o <<= 1) {
        int t = __shfl_up(inc, o, 64);
        if (lane >= o) inc += t;
    }

    if (lane == 0)  cw[wid] = csum;
    if (lane == 63) wv[wid] = inc;
    __syncthreads();

    int base = 0;
    #pragma unroll
    for (int w = 0; w < SCAN_BS / 64; ++w) {
        base += cw[w];
        if (w < wid) base += wv[w];
    }

    if (gid < C) {
        const int end = base + inc;     // inclusive cumsum
        offsets[gid] = end;
        const int start = end - v;
        int s0 = ((start + OBJ_BS - 1) / OBJ_BS) * OBJ_BS;
        for (int s = s0; s < end; s += OBJ_BS) blockCav[s / OBJ_BS] = gid;
    }
}

// ---------------- main per-object kernel (R3 verbatim — best measured) ----------------
//
// out layout (floats):
//   [0,       8N)  obj_input  [1,N,2,4]
//   [8N,     10N)  query      [1,N,1,2]
//   [10N,    12N)  time_encode[N,2]
//   [12N,    13N)  target_time_diff [N]

__global__ __launch_bounds__(OBJ_BS) void motion_kernel(
    const float* __restrict__ bbx, const float* __restrict__ tint,
    const int* __restrict__ offsets, const int* __restrict__ blockCav,
    int C, int N, float* __restrict__ out) {

    __shared__ __align__(16) float sb[SLAB_F];
    __shared__ int   soff[OBJ_BS + 1];        // offsets[c_lo .. c_lo+256]
    __shared__ float st[3 * (OBJ_BS + 1)];    // tint rows for those cavs (771)

    const int tid  = threadIdx.x;
    const int lane = tid & 63;
    const int wid  = tid >> 6;
    const long long blockStart = (long long)blockIdx.x * OBJ_BS;
    const int nObjBlk = (int)min((long long)OBJ_BS, (long long)N - blockStart);

    const int c_lo = blockCav[blockIdx.x];    // uniform -> scalar load

    // ---- issue bbx slab DMA (fire-and-forget, no VGPR round trip) ----
    const float* gsrc = bbx + blockStart * 21;
    if (nObjBlk == OBJ_BS) {
        #pragma unroll
        for (int ch = wid; ch < SLAB_CH; ch += 4)
            gload_lds16((const void*)(gsrc + ch * 256 + lane * 4), (void*)(sb + ch * 256));
    } else {
        // tail fallback (not hit when N % 256 == 0)
        const int nElem = nObjBlk * 21;
        for (int k = tid; k < nElem; k += OBJ_BS) sb[k] = gsrc[k];
    }

    // ---- side loads: all issued independently, then LDS writes ----
    const int c = c_lo + tid;
    const int offv = (c < C) ? offsets[c] : INT_MAX;
    int off_last = INT_MAX;
    if (tid == 0) {
        int c2 = c_lo + OBJ_BS;
        off_last = (c2 < C) ? offsets[c2] : INT_MAX;
    }
    const int base3 = 3 * c_lo;
    const int lim3  = 3 * C - base3;
    const float tv0 = (tid < lim3)       ? tint[base3 + tid]       : 0.0f;
    const float tv1 = (tid + 256 < lim3) ? tint[base3 + tid + 256] : 0.0f;
    const float tv2 = (tid + 512 < lim3) ? tint[base3 + tid + 512] : 0.0f;
    float tv3 = 0.0f;
    if (tid < 3 && tid + 768 < lim3) tv3 = tint[base3 + tid + 768];

    soff[tid] = offv;
    if (tid == 0) soff[OBJ_BS] = off_last;
    st[tid]       = tv0;
    st[tid + 256] = tv1;
    st[tid + 512] = tv2;
    if (tid < 3) st[tid + 768] = tv3;

    __syncthreads();   // drains DMA (vmcnt) + LDS writes

    if (tid >= nObjBlk) return;
    const int i = (int)(blockStart + tid);

    // binary search in LDS: first j in [0,257) with soff[j] > i
    int lo = 0, hi = OBJ_BS + 1;
    while (lo < hi) {
        int mid = (lo + hi) >> 1;
        if (soff[mid] > i) hi = mid; else lo = mid + 1;
    }
    const int j = lo;
    const float t0 = st[3 * j + 0];
    const float t1 = st[3 * j + 1];
    const float t2 = st[3 * j + 2];

    // td_rep = [t2, t1, t0];  dt = time_encode
    const float dt0 = t1 - t2;
    const float dt1 = t0 - t1;

    // frames from LDS: frame k at sb[tid*21 + k*7 + {0,1}]  (stride 21 -> conflict-free)
    const float* b = sb + tid * 21;
    const float x0 = b[0],  y0 = b[1];
    const float x1 = b[7],  y1 = b[8];
    const float x2 = b[14], y2 = b[15];

    // coords (flipped, normalized to last): c0 = bbx2-bbx0, c1 = bbx1-bbx0, c2 = 0
    const float c0x = x2 - x0, c0y = y2 - y0;
    const float c1x = x1 - x0, c1y = y1 - y0;

    const float d0x = c1x - c0x, d0y = c1y - c0y;
    const float d1x = 0.0f - c1x, d1y = 0.0f - c1y;

    const float s0x = d0x / dt0, s0y = d0y / dt0;
    const float s1x = d1x / dt1, s1y = d1y / dt1;

    const float last_len = 0.0f - (t1 - t0);
    const float safe_len = (last_len == 0.0f) ? 1.0f : last_len;
    const float exx = ((0.0f - c1x) * (0.0f - t0)) / safe_len;
    const float exy = ((0.0f - c1y) * (0.0f - t0)) / safe_len;
    const float qx = (last_len == 0.0f) ? 0.0f : exx;
    const float qy = (last_len == 0.0f) ? 0.0f : exy;

    // ---- writes ----
    const size_t Ns = (size_t)N;
    float4* oi = (float4*)out;
    oi[(size_t)i * 2 + 0] = make_float4(d0x, d0y, s0x, s0y);
    oi[(size_t)i * 2 + 1] = make_float4(d1x, d1y, s1x, s1y);

    float2* q  = (float2*)(out + 8 * Ns);
    q[i] = make_float2(qx, qy);

    float2* te = (float2*)(out + 10 * Ns);
    te[i] = make_float2(dt0, dt1);

    out[12 * Ns + (size_t)i] = 0.0f - t0;
}

// ---------------- launch ----------------

extern "C" void kernel_launch(void* const* d_in, const int* in_sizes, int n_in,
                              void* d_out, int out_size, void* d_ws, size_t ws_size,
                              hipStream_t stream) {
    const float* bbx  = (const float*)d_in[0];   // [N,3,7]
    const float* tint = (const float*)d_in[1];   // [C*3]
    const int*   cnt  = (const int*)d_in[2];     // [C]
    float* out = (float*)d_out;

    const int N = in_sizes[0] / 21;
    const int C = in_sizes[2];

    const int nb  = (C + SCAN_BS - 1) / SCAN_BS;
    const int nob = (N + OBJ_BS - 1) / OBJ_BS;

    // ws layout: offsets[C] | pad 64 | blockCav[nob]
    int* offsets  = (int*)d_ws;
    int* blockCav = offsets + C + 64;

    scan_fused_kernel<<<nb, SCAN_BS, 0, stream>>>(cnt, C, offsets, blockCav);
    motion_kernel<<<nob, OBJ_BS, 0, stream>>>(bbx, tint, offsets, blockCav, C, N, out);
}

// Round 9
// 34.545 us; speedup vs baseline: 1.7585x; 1.7306x over previous
//
#include <hip/hip_runtime.h>
#include <limits.h>
#include <stdint.h>

#define SCAN_BS 256
#define OBJ_BS  256
#define SLAB_F  (OBJ_BS * 21)     // 5376 floats = 21504 B
#define SLAB_CH (SLAB_F / 256)    // 21 wave-chunks (64 lanes x 16 B)

// ---- global->LDS DMA helper (size must be a literal) ----
__device__ __forceinline__ void gload_lds16(const void* g, void* l) {
    __builtin_amdgcn_global_load_lds(
        (const __attribute__((address_space(1))) uint32_t*)g,
        (__attribute__((address_space(3))) uint32_t*)l, 16, 0, 0);
}

// ---------------- hierarchical scan, stage 1: per-chunk sums ----------------
__global__ __launch_bounds__(SCAN_BS) void chunk_sum_kernel(
    const int* __restrict__ counts, int C, int* __restrict__ chunkSum) {

    __shared__ int ws[SCAN_BS / 64];
    const int tid  = threadIdx.x;
    const int lane = tid & 63;
    const int wid  = tid >> 6;
    const int gid  = blockIdx.x * SCAN_BS + tid;

    int v = (gid < C) ? counts[gid] : 0;
    #pragma unroll
    for (int o = 32; o > 0; o >>= 1) v += __shfl_down(v, o, 64);
    if (lane == 0) ws[wid] = v;
    __syncthreads();
    if (tid == 0) chunkSum[blockIdx.x] = ws[0] + ws[1] + ws[2] + ws[3];
}

// ---------------- hierarchical scan, stage 2: scan + emit ----------------
// carry = sum(chunkSum[0..b)) via one predicated coalesced load + reduce (nb <= 256);
// within-chunk inclusive scan via wave shuffles; emits offsets[] and blockCav[].
__global__ __launch_bounds__(SCAN_BS) void scan_emit_kernel(
    const int* __restrict__ counts, const int* __restrict__ chunkSum,
    int C, int nb, int* __restrict__ offsets, int* __restrict__ blockCav) {

    __shared__ int cw[SCAN_BS / 64];   // per-wave carry partials
    __shared__ int wv[SCAN_BS / 64];   // per-wave chunk totals

    const int tid  = threadIdx.x;
    const int lane = tid & 63;
    const int wid  = tid >> 6;
    const int b    = blockIdx.x;
    const int gid  = b * SCAN_BS + tid;

    // carry over preceding chunks (<=1 element per thread when nb <= SCAN_BS)
    int cs = 0;
    for (int j = tid; j < b; j += SCAN_BS) cs += chunkSum[j];
    #pragma unroll
    for (int o = 32; o > 0; o >>= 1) cs += __shfl_down(cs, o, 64);

    // wave-level inclusive scan of own count
    const int v = (gid < C) ? counts[gid] : 0;
    int inc = v;
    #pragma unroll
    for (int o = 1; o < 64; o <<= 1) {
        int t = __shfl_up(inc, o, 64);
        if (lane >= o) inc += t;
    }

    if (lane == 0)  cw[wid] = cs;
    if (lane == 63) wv[wid] = inc;
    __syncthreads();

    int base = 0;
    #pragma unroll
    for (int w = 0; w < SCAN_BS / 64; ++w) {
        base += cw[w];
        if (w < wid) base += wv[w];
    }

    if (gid < C) {
        const int end = base + inc;     // inclusive cumsum
        offsets[gid] = end;
        const int start = end - v;
        int s0 = ((start + OBJ_BS - 1) / OBJ_BS) * OBJ_BS;
        for (int s = s0; s < end; s += OBJ_BS) blockCav[s / OBJ_BS] = gid;
    }
}

// ---------------- main per-object kernel (R3 verbatim — best measured) ----------------
//
// out layout (floats):
//   [0,       8N)  obj_input  [1,N,2,4]
//   [8N,     10N)  query      [1,N,1,2]
//   [10N,    12N)  time_encode[N,2]
//   [12N,    13N)  target_time_diff [N]

__global__ __launch_bounds__(OBJ_BS) void motion_kernel(
    const float* __restrict__ bbx, const float* __restrict__ tint,
    const int* __restrict__ offsets, const int* __restrict__ blockCav,
    int C, int N, float* __restrict__ out) {

    __shared__ __align__(16) float sb[SLAB_F];
    __shared__ int   soff[OBJ_BS + 1];        // offsets[c_lo .. c_lo+256]
    __shared__ float st[3 * (OBJ_BS + 1)];    // tint rows for those cavs (771)

    const int tid  = threadIdx.x;
    const int lane = tid & 63;
    const int wid  = tid >> 6;
    const long long blockStart = (long long)blockIdx.x * OBJ_BS;
    const int nObjBlk = (int)min((long long)OBJ_BS, (long long)N - blockStart);

    const int c_lo = blockCav[blockIdx.x];    // uniform -> scalar load

    // ---- issue bbx slab DMA (fire-and-forget, no VGPR round trip) ----
    const float* gsrc = bbx + blockStart * 21;
    if (nObjBlk == OBJ_BS) {
        #pragma unroll
        for (int ch = wid; ch < SLAB_CH; ch += 4)
            gload_lds16((const void*)(gsrc + ch * 256 + lane * 4), (void*)(sb + ch * 256));
    } else {
        // tail fallback (not hit when N % 256 == 0)
        const int nElem = nObjBlk * 21;
        for (int k = tid; k < nElem; k += OBJ_BS) sb[k] = gsrc[k];
    }

    // ---- side loads: all issued independently, then LDS writes ----
    const int c = c_lo + tid;
    const int offv = (c < C) ? offsets[c] : INT_MAX;
    int off_last = INT_MAX;
    if (tid == 0) {
        int c2 = c_lo + OBJ_BS;
        off_last = (c2 < C) ? offsets[c2] : INT_MAX;
    }
    const int base3 = 3 * c_lo;
    const int lim3  = 3 * C - base3;
    const float tv0 = (tid < lim3)       ? tint[base3 + tid]       : 0.0f;
    const float tv1 = (tid + 256 < lim3) ? tint[base3 + tid + 256] : 0.0f;
    const float tv2 = (tid + 512 < lim3) ? tint[base3 + tid + 512] : 0.0f;
    float tv3 = 0.0f;
    if (tid < 3 && tid + 768 < lim3) tv3 = tint[base3 + tid + 768];

    soff[tid] = offv;
    if (tid == 0) soff[OBJ_BS] = off_last;
    st[tid]       = tv0;
    st[tid + 256] = tv1;
    st[tid + 512] = tv2;
    if (tid < 3) st[tid + 768] = tv3;

    __syncthreads();   // drains DMA (vmcnt) + LDS writes

    if (tid >= nObjBlk) return;
    const int i = (int)(blockStart + tid);

    // binary search in LDS: first j in [0,257) with soff[j] > i
    int lo = 0, hi = OBJ_BS + 1;
    while (lo < hi) {
        int mid = (lo + hi) >> 1;
        if (soff[mid] > i) hi = mid; else lo = mid + 1;
    }
    const int j = lo;
    const float t0 = st[3 * j + 0];
    const float t1 = st[3 * j + 1];
    const float t2 = st[3 * j + 2];

    // td_rep = [t2, t1, t0];  dt = time_encode
    const float dt0 = t1 - t2;
    const float dt1 = t0 - t1;

    // frames from LDS: frame k at sb[tid*21 + k*7 + {0,1}]  (stride 21 -> conflict-free)
    const float* b = sb + tid * 21;
    const float x0 = b[0],  y0 = b[1];
    const float x1 = b[7],  y1 = b[8];
    const float x2 = b[14], y2 = b[15];

    // coords (flipped, normalized to last): c0 = bbx2-bbx0, c1 = bbx1-bbx0, c2 = 0
    const float c0x = x2 - x0, c0y = y2 - y0;
    const float c1x = x1 - x0, c1y = y1 - y0;

    const float d0x = c1x - c0x, d0y = c1y - c0y;
    const float d1x = 0.0f - c1x, d1y = 0.0f - c1y;

    const float s0x = d0x / dt0, s0y = d0y / dt0;
    const float s1x = d1x / dt1, s1y = d1y / dt1;

    const float last_len = 0.0f - (t1 - t0);
    const float safe_len = (last_len == 0.0f) ? 1.0f : last_len;
    const float exx = ((0.0f - c1x) * (0.0f - t0)) / safe_len;
    const float exy = ((0.0f - c1y) * (0.0f - t0)) / safe_len;
    const float qx = (last_len == 0.0f) ? 0.0f : exx;
    const float qy = (last_len == 0.0f) ? 0.0f : exy;

    // ---- writes ----
    const size_t Ns = (size_t)N;
    float4* oi = (float4*)out;
    oi[(size_t)i * 2 + 0] = make_float4(d0x, d0y, s0x, s0y);
    oi[(size_t)i * 2 + 1] = make_float4(d1x, d1y, s1x, s1y);

    float2* q  = (float2*)(out + 8 * Ns);
    q[i] = make_float2(qx, qy);

    float2* te = (float2*)(out + 10 * Ns);
    te[i] = make_float2(dt0, dt1);

    out[12 * Ns + (size_t)i] = 0.0f - t0;
}

// ---------------- launch ----------------

extern "C" void kernel_launch(void* const* d_in, const int* in_sizes, int n_in,
                              void* d_out, int out_size, void* d_ws, size_t ws_size,
                              hipStream_t stream) {
    const float* bbx  = (const float*)d_in[0];   // [N,3,7]
    const float* tint = (const float*)d_in[1];   // [C*3]
    const int*   cnt  = (const int*)d_in[2];     // [C]
    float* out = (float*)d_out;

    const int N = in_sizes[0] / 21;
    const int C = in_sizes[2];

    const int nb  = (C + SCAN_BS - 1) / SCAN_BS;
    const int nob = (N + OBJ_BS - 1) / OBJ_BS;

    // ws layout: offsets[C] | pad 64 | blockCav[nob] | pad 64 | chunkSum[nb]
    int* offsets  = (int*)d_ws;
    int* blockCav = offsets + C + 64;
    int* chunkSum = blockCav + nob + 64;

    chunk_sum_kernel<<<nb, SCAN_BS, 0, stream>>>(cnt, C, chunkSum);
    scan_emit_kernel<<<nb, SCAN_BS, 0, stream>>>(cnt, chunkSum, C, nb, offsets, blockCav);
    motion_kernel<<<nob, OBJ_BS, 0, stream>>>(bbx, tint, offsets, blockCav, C, N, out);
}

// Round 12
// 34.395 us; speedup vs baseline: 1.7662x; 1.0044x over previous
//
#include <hip/hip_runtime.h>
#include <limits.h>
#include <stdint.h>

#define SCAN_BS  256
#define MOT_BS   256
#define WAVE_OBJ 64
#define WSLAB_F  (WAVE_OBJ * 21)   // 1344 floats = 5376 B per wave slab

// ---- global->LDS DMA helpers (size must be a literal) ----
__device__ __forceinline__ void gload_lds16(const void* g, void* l) {
    __builtin_amdgcn_global_load_lds(
        (const __attribute__((address_space(1))) uint32_t*)g,
        (__attribute__((address_space(3))) uint32_t*)l, 16, 0, 0);
}
__device__ __forceinline__ void gload_lds4(const void* g, void* l) {
    __builtin_amdgcn_global_load_lds(
        (const __attribute__((address_space(1))) uint32_t*)g,
        (__attribute__((address_space(3))) uint32_t*)l, 4, 0, 0);
}

// ---------------- hierarchical scan, stage 1: per-chunk sums ----------------
__global__ __launch_bounds__(SCAN_BS) void chunk_sum_kernel(
    const int* __restrict__ counts, int C, int* __restrict__ chunkSum) {

    __shared__ int ws[SCAN_BS / 64];
    const int tid  = threadIdx.x;
    const int lane = tid & 63;
    const int wid  = tid >> 6;
    const int gid  = blockIdx.x * SCAN_BS + tid;

    int v = (gid < C) ? counts[gid] : 0;
    #pragma unroll
    for (int o = 32; o > 0; o >>= 1) v += __shfl_down(v, o, 64);
    if (lane == 0) ws[wid] = v;
    __syncthreads();
    if (tid == 0) chunkSum[blockIdx.x] = ws[0] + ws[1] + ws[2] + ws[3];
}

// ---------------- hierarchical scan, stage 2: scan + emit ----------------
__global__ __launch_bounds__(SCAN_BS) void scan_emit_kernel(
    const int* __restrict__ counts, const int* __restrict__ chunkSum,
    int C, int* __restrict__ offsets, int* __restrict__ waveCav) {

    __shared__ int cw[SCAN_BS / 64];
    __shared__ int wv[SCAN_BS / 64];

    const int tid  = threadIdx.x;
    const int lane = tid & 63;
    const int wid  = tid >> 6;
    const int b    = blockIdx.x;
    const int gid  = b * SCAN_BS + tid;

    int cs = 0;
    for (int j = tid; j < b; j += SCAN_BS) cs += chunkSum[j];
    #pragma unroll
    for (int o = 32; o > 0; o >>= 1) cs += __shfl_down(cs, o, 64);

    const int v = (gid < C) ? counts[gid] : 0;
    int inc = v;
    #pragma unroll
    for (int o = 1; o < 64; o <<= 1) {
        int t = __shfl_up(inc, o, 64);
        if (lane >= o) inc += t;
    }

    if (lane == 0)  cw[wid] = cs;
    if (lane == 63) wv[wid] = inc;
    __syncthreads();

    int base = 0;
    #pragma unroll
    for (int w = 0; w < SCAN_BS / 64; ++w) {
        base += cw[w];
        if (w < wid) base += wv[w];
    }

    if (gid < C) {
        const int end = base + inc;     // inclusive cumsum
        offsets[gid] = end;
        const int start = end - v;
        int s0 = ((start + WAVE_OBJ - 1) / WAVE_OBJ) * WAVE_OBJ;
        for (int s = s0; s < end; s += WAVE_OBJ) waveCav[s / WAVE_OBJ] = gid;
    }
}

// ---------------- main per-object kernel ----------------
// Per-wave DMA staging + branchless counting search (6 shuffles, provably exact);
// proven __syncthreads drain. All threads reach the barrier.
//
// out layout (floats):
//   [0,       8N)  obj_input  [1,N,2,4]
//   [8N,     10N)  query      [1,N,1,2]
//   [10N,    12N)  time_encode[N,2]
//   [12N,    13N)  target_time_diff [N]

__global__ __launch_bounds__(MOT_BS) void motion_kernel(
    const float* __restrict__ bbx, const float* __restrict__ tint,
    const int* __restrict__ offsets, const int* __restrict__ waveCav,
    int C, int N, float* __restrict__ out) {

    __shared__ __align__(16) float sb[(MOT_BS / 64) * WSLAB_F];   // 21504 B -> 7 blocks/CU

    const int tid  = threadIdx.x;
    const int lane = tid & 63;
    const int wid  = tid >> 6;
    const int w    = blockIdx.x * (MOT_BS / 64) + wid;   // global wave id
    const int objBase = w * WAVE_OBJ;
    const int i = objBase + lane;
    const bool fullWave = (objBase + WAVE_OBJ <= N);

    int cav = 0;
    float t0 = 1.0f, t1 = 1.0f, t2 = 1.0f;

    if (fullWave) {
        // ---- wave-local DMA staging (fire-and-forget) ----
        const int c0 = waveCav[w];
        float* slab = sb + wid * WSLAB_F;
        const float* gw = bbx + (size_t)objBase * 21;    // objBase*84 B -> 16B aligned
        #pragma unroll
        for (int ch = 0; ch < 5; ++ch)
            gload_lds16((const void*)(gw + ch * 256 + lane * 4), (void*)(slab + ch * 256));
        gload_lds4((const void*)(gw + 1280 + lane), (void*)(slab + 1280));

        // offsets window in registers (wave spans cavs [c0, c0+63])
        const int cc   = c0 + lane;
        const int offv = (cc < C) ? offsets[cc] : INT_MAX;

        // branchless counting lower_bound: k = #entries <= i  (answer in [0,63])
        // tests offv[k+s-1]; k+s-1 <= 63 always since accepted s-bits are disjoint.
        int k = 0;
        #pragma unroll
        for (int s = 32; s >= 1; s >>= 1) {
            const int vt = __shfl(offv, k + s - 1, 64);
            if (vt <= i) k += s;
        }
        cav = c0 + k;

        // per-lane time gather, overlapped with DMA flight
        t0 = tint[3 * cav + 0];
        t1 = tint[3 * cav + 1];
        t2 = tint[3 * cav + 2];
    }

    __syncthreads();   // proven drain: vmcnt(0) + lgkmcnt(0) + s_barrier

    if (i >= N) return;

    float x0, y0, x1, y1, x2, y2;
    if (fullWave) {
        // 6 LDS reads, stride 21 words -> 2 lanes/bank = conflict-free
        const float* bp = sb + wid * WSLAB_F + lane * 21;
        x0 = bp[0];  y0 = bp[1];
        x1 = bp[7];  y1 = bp[8];
        x2 = bp[14]; y2 = bp[15];
    } else {
        // tail path (not hit when N % 64 == 0)
        int lo = 0, hi = C;
        while (lo < hi) {
            const int mid = (lo + hi) >> 1;
            if (offsets[mid] > i) hi = mid; else lo = mid + 1;
        }
        cav = lo;
        t0 = tint[3 * cav + 0];
        t1 = tint[3 * cav + 1];
        t2 = tint[3 * cav + 2];
        const float* bp = bbx + (size_t)i * 21;
        x0 = bp[0];  y0 = bp[1];
        x1 = bp[7];  y1 = bp[8];
        x2 = bp[14]; y2 = bp[15];
    }

    // td_rep = [t2, t1, t0];  dt = time_encode
    const float dt0 = t1 - t2;
    const float dt1 = t0 - t1;

    // coords (flipped, normalized to last): c0v = f2-f0, c1v = f1-f0, c2v = 0
    const float c0x = x2 - x0, c0y = y2 - y0;
    const float c1x = x1 - x0, c1y = y1 - y0;

    const float d0x = c1x - c0x, d0y = c1y - c0y;
    const float d1x = 0.0f - c1x, d1y = 0.0f - c1y;

    const float s0x = d0x / dt0, s0y = d0y / dt0;
    const float s1x = d1x / dt1, s1y = d1y / dt1;

    const float last_len = 0.0f - (t1 - t0);
    const float safe_len = (last_len == 0.0f) ? 1.0f : last_len;
    const float exx = ((0.0f - c1x) * (0.0f - t0)) / safe_len;
    const float exy = ((0.0f - c1y) * (0.0f - t0)) / safe_len;
    const float qx = (last_len == 0.0f) ? 0.0f : exx;
    const float qy = (last_len == 0.0f) ? 0.0f : exy;

    // ---- writes (all coalesced within the wave) ----
    const size_t Ns = (size_t)N;
    float4* oi = (float4*)out;
    oi[(size_t)i * 2 + 0] = make_float4(d0x, d0y, s0x, s0y);
    oi[(size_t)i * 2 + 1] = make_float4(d1x, d1y, s1x, s1y);

    float2* q  = (float2*)(out + 8 * Ns);
    q[i] = make_float2(qx, qy);

    float2* te = (float2*)(out + 10 * Ns);
    te[i] = make_float2(dt0, dt1);

    out[12 * Ns + (size_t)i] = 0.0f - t0;
}

// ---------------- launch ----------------

extern "C" void kernel_launch(void* const* d_in, const int* in_sizes, int n_in,
                              void* d_out, int out_size, void* d_ws, size_t ws_size,
                              hipStream_t stream) {
    const float* bbx  = (const float*)d_in[0];   // [N,3,7]
    const float* tint = (const float*)d_in[1];   // [C*3]
    const int*   cnt  = (const int*)d_in[2];     // [C]
    float* out = (float*)d_out;

    const int N = in_sizes[0] / 21;
    const int C = in_sizes[2];

    const int nb     = (C + SCAN_BS - 1) / SCAN_BS;
    const int nWaves = (N + WAVE_OBJ - 1) / WAVE_OBJ;
    const int nob    = (nWaves * WAVE_OBJ + MOT_BS - 1) / MOT_BS;

    // ws layout: offsets[C] | pad 64 | waveCav[nWaves] | pad 64 | chunkSum[nb]
    int* offsets  = (int*)d_ws;
    int* waveCav  = offsets + C + 64;
    int* chunkSum = waveCav + nWaves + 64;

    chunk_sum_kernel<<<nb, SCAN_BS, 0, stream>>>(cnt, C, chunkSum);
    scan_emit_kernel<<<nb, SCAN_BS, 0, stream>>>(cnt, chunkSum, C, offsets, waveCav);
    motion_kernel<<<nob, MOT_BS, 0, stream>>>(bbx, tint, offsets, waveCav, C, N, out);
}